// Round 11
// baseline (417.728 us; speedup 1.0000x reference)
//
#include <hip/hip_runtime.h>

#define NODES    16384
#define EDGES    262144
#define OUT_CH   304      // 64 + 32*3 + 16*9
#define EB       16       // edges per block
#define NTHREADS 256

typedef __attribute__((ext_vector_type(8))) short short8;
typedef __attribute__((ext_vector_type(4))) float f32x4;
typedef __attribute__((ext_vector_type(8))) float f32x8;
typedef __attribute__((ext_vector_type(8))) __bf16 bf16x8;
#define MFMA(a,b,c) __builtin_amdgcn_mfma_f32_16x16x32_bf16((a),(b),(c),0,0,0)

// ---------- packed-B (bf16) sizes ----------
#define NB1 100352
#define NB2 36864
#define NB3 2048
#define NPACK (NB1 + NB2 + NB3)     // 139264 ushort = 278528 B

// ---------------- fused prepack(B) + count kernel ----------------
// K-order: k = b*8 + l  (fragment of 8 consecutive k = one b, all 8 l)
__global__ __launch_bounds__(256) void prep_kernel(
    const float* __restrict__ P000, const float* __restrict__ P110, const float* __restrict__ P220,
    const float* __restrict__ P011, const float* __restrict__ P101, const float* __restrict__ P121,
    const float* __restrict__ P211, const float* __restrict__ P111,
    const float* __restrict__ P022, const float* __restrict__ P112, const float* __restrict__ P202,
    const float* __restrict__ P222, const float* __restrict__ P212,
    unsigned short* __restrict__ BP,
    const int* __restrict__ dst, int* __restrict__ cnt)
{
    int idx = blockIdx.x*256 + threadIdx.x;
    if (idx < NPACK) {
        float v = 0.0f;
        if (idx < NB1) {                       // GEMM1: BW=112
            int j = idx & 7, lane = (idx >> 3) & 63, q = idx >> 9;
            int tile = q % 7, kk = q / 7;
            int n = tile*16 + (lane & 15);
            int k = kk*32 + (lane >> 4)*8 + j;
            int l = k & 7, b = k >> 3;
            if (n < 64) {           int c = n;
                if      (b <  64) v = P000[(c*8+l)*64 + b];
                else if (b <  96) v = P110[(c*8+l)*32 + (b-64)];
                else              v = P220[(c*8+l)*16 + (b-96)];
            } else if (n < 96) {    int c = n - 64;      // as0
                if      (b <  64) v = P101[(c*8+l)*64 + b];
                else if (b <  96) v = P211[(c*8+l)*32 + (b-64)];
            } else {                int c = n - 96;      // a00
                if      (b <  64) v = P202[(c*8+l)*64 + b];
            }
        } else if (idx < NB1 + NB2) {          // GEMM2: BW=96
            int o = idx - NB1;
            int j = o & 7, lane = (o >> 3) & 63, q = o >> 9;
            int tile = q % 3, kk = q / 3;
            int n = tile*16 + (lane & 15);
            int k = kk*32 + (lane >> 4)*8 + j;
            int l = k & 7, b = k >> 3;
            if (n < 32) {           int c = n;           // av
                if      (b <  32) v = P011[(c*8+l)*32 + b];
                else if (b <  48) v = P121[(c*8+l)*16 + (b-32)];
                else if (b <  80) v = P111[(c*8+l)*32 + (b-48)];
            } else {                int c = n - 32;      // aj
                if      (b <  32) v = P112[(c*8+l)*32 + b];
                else if (b <  48) v = 0.0f;
                else if (b <  80) v = P212[(c*8+l)*32 + (b-48)];
                else              v = P222[(c*8+l)*16 + (b-80)];
            }
        } else {                               // GEMM3: BW=16
            int o = idx - NB1 - NB2;
            int j = o & 7, lane = (o >> 3) & 63, kk = o >> 9;
            int n = lane & 15;
            int k = kk*32 + (lane >> 4)*8 + j;
            int l = k & 7, b = k >> 3;
            v = P022[(n*8+l)*16 + b];
        }
        union { float f; unsigned int i; } x; x.f = v;
        unsigned int i = x.i;
        i += 0x7fffu + ((i >> 16) & 1u);
        BP[idx] = (unsigned short)(i >> 16);
    }
    if (idx < EDGES) atomicAdd(&cnt[dst[idx]], 1);
}

// ---------------- CSR scan + scatter (verified) ----------------
__global__ __launch_bounds__(256) void scan_kernel(const int* __restrict__ cnt,
                                                   int* __restrict__ off,
                                                   int* __restrict__ cursor)
{
    __shared__ int s_part[256];
    const int t = threadIdx.x;
    const int base = t * 64;
    int sum = 0;
    for (int i = 0; i < 64; ++i) sum += cnt[base + i];
    s_part[t] = sum;
    __syncthreads();
    for (int d = 1; d < 256; d <<= 1) {
        int add = (t >= d) ? s_part[t - d] : 0;
        __syncthreads();
        s_part[t] += add;
        __syncthreads();
    }
    int run = s_part[t] - sum;
    for (int i = 0; i < 64; ++i) {
        int c = cnt[base + i];
        off[base + i]    = run;
        cursor[base + i] = run;
        run += c;
    }
    if (t == 255) off[NODES] = run;
}

__global__ __launch_bounds__(256) void scatter_kernel(const int* __restrict__ dst,
                                                      int* __restrict__ cursor,
                                                      int* __restrict__ eidx)
{
    int e = blockIdx.x*256 + threadIdx.x;
    if (e < EDGES) {
        int pos = atomicAdd(&cursor[dst[e]], 1);
        eidx[pos] = e;
    }
}

// A-fragment: one feature element x the full (in-register) rad vector
__device__ __forceinline__ short8 build2(const f32x8 radv, float f)
{
    f32x8 z = radv * f;
    bf16x8 zb = __builtin_convertvector(z, bf16x8);
    union { bf16x8 b; short8 s; } w; w.b = zb;
    return w.s;
}

// feature pool (dead after GEMM loops) unioned with result staging
struct FeatPool {
    float FS[EB][116];       // xa[0,64) sv[64,96) sd[96,112)
    float FVT[EB][3][100];   // [i][b]: xv[0,32) uv[32,48) cr[48,80) wd[80,96)
};                           // 26624 B
struct MsgPool {
    float m[EB][308];        // 19712 B
    float as0[EB][32];       //  2048 B
    float a00[EB][16];       //  1024 B
    float aj[EB][3][16];     //  3072 B
};                           // 25856 B
union Pool {
    FeatPool f;
    MsgPool  g;
};

// ---------------- main edge kernel: MFMA, register-resident feats, 4 blocks/CU ----------------
__global__ __launch_bounds__(NTHREADS, 4) void edge_kernel(
    const float* __restrict__ xa_g, const float* __restrict__ xv_g, const float* __restrict__ xd_g,
    const float* __restrict__ rij_g,
    const unsigned short* __restrict__ BP,
    const int* __restrict__ src, const int* __restrict__ dst, const int* __restrict__ eidx,
    float* __restrict__ out)
{
    __shared__ __align__(16) Pool s_p;
    __shared__ __align__(16) float s_FDT[EB][9][20];   // [ij][b<16]
    __shared__ float s_rad[EB][9];
    __shared__ float s_rh[EB][4];
    __shared__ int   s_dst[EB];
    __shared__ int   s_srcn[EB];

    const int t  = threadIdx.x;
    const int e0 = blockIdx.x * EB;
    const int lane = t & 63, wid = t >> 6;
    const int col = lane & 15, quad = lane >> 4;

    const short8* __restrict__ B1 = (const short8*)BP;
    const short8* __restrict__ B2 = (const short8*)(BP + NB1);
    const short8* __restrict__ B3 = (const short8*)(BP + NB1 + NB2);

    // ---- phase 1a: per-edge radial basis + rh ----
    if (t < EB) {
        const int e = eidx[e0 + t];            // CSR order: s_dst non-decreasing
        float r0 = rij_g[e*3+0];
        float r1 = rij_g[e*3+1];
        float r2 = rij_g[e*3+2];
        float x_sq = (r0*r0 + r1*r1 + r2*r2) * 0.125f;
        float q  = sqrtf(x_sq);
        float w  = fmaxf(1.0f - x_sq, 0.0f);
        const float PI = 3.14159265358979323846f;
        for (int n = 0; n < 8; ++n)
            s_rad[t][n] = cosf(PI * (float)n * q) * w;
        float y0 = r0*0.875f, y1 = r1*0.875f, y2 = r2*0.875f;
        float nn = sqrtf(y0*y0 + y1*y1 + y2*y2);
        float sc = tanhf(nn) / fmaxf(nn, 1e-6f);
        s_rh[t][0] = y0*sc; s_rh[t][1] = y1*sc; s_rh[t][2] = y2*sc; s_rh[t][3] = 0.f;
        s_dst[t]  = dst[e];
        s_srcn[t] = src[e];
    }
    __syncthreads();

    // ---- phase 1b: gather node features into LDS (verified math/layout) ----
    {
        const int el  = t >> 4;
        const int sub = t & 15;
        const int n   = s_srcn[el];
        const float rh0 = s_rh[el][0], rh1 = s_rh[el][1], rh2 = s_rh[el][2];
        #pragma unroll
        for (int k = 0; k < 4; ++k) {
            int b = sub + 16*k;
            s_p.f.FS[el][b] = xa_g[n*64 + b];
        }
        #pragma unroll
        for (int k = 0; k < 2; ++k) {
            int b = sub + 16*k;
            float v0 = xv_g[(n*32 + b)*3 + 0];
            float v1 = xv_g[(n*32 + b)*3 + 1];
            float v2 = xv_g[(n*32 + b)*3 + 2];
            s_p.f.FVT[el][0][b] = v0;
            s_p.f.FVT[el][1][b] = v1;
            s_p.f.FVT[el][2][b] = v2;
            s_p.f.FS[el][64 + b] = rh0*v0 + rh1*v1 + rh2*v2;      // sv
            s_p.f.FVT[el][0][48 + b] = rh1*v2 - rh2*v1;           // cr
            s_p.f.FVT[el][1][48 + b] = rh2*v0 - rh0*v2;
            s_p.f.FVT[el][2][48 + b] = rh0*v1 - rh1*v0;
        }
        {
            const int b = sub;
            const float d0 = xd_g[(n*16+b)*9+0], d1 = xd_g[(n*16+b)*9+1], d2 = xd_g[(n*16+b)*9+2];
            const float d3 = xd_g[(n*16+b)*9+3], d4 = xd_g[(n*16+b)*9+4], d5 = xd_g[(n*16+b)*9+5];
            const float d6 = xd_g[(n*16+b)*9+6], d7 = xd_g[(n*16+b)*9+7], d8 = xd_g[(n*16+b)*9+8];
            s_FDT[el][0][b]=d0; s_FDT[el][1][b]=d1; s_FDT[el][2][b]=d2;
            s_FDT[el][3][b]=d3; s_FDT[el][4][b]=d4; s_FDT[el][5][b]=d5;
            s_FDT[el][6][b]=d6; s_FDT[el][7][b]=d7; s_FDT[el][8][b]=d8;
            const float uv0 = d0*rh0 + d1*rh1 + d2*rh2;
            const float uv1 = d3*rh0 + d4*rh1 + d5*rh2;
            const float uv2 = d6*rh0 + d7*rh1 + d8*rh2;
            s_p.f.FVT[el][0][32 + b] = uv0;
            s_p.f.FVT[el][1][32 + b] = uv1;
            s_p.f.FVT[el][2][32 + b] = uv2;
            s_p.f.FVT[el][0][80 + b] = rh0*d0 + rh1*d3 + rh2*d6;  // wd
            s_p.f.FVT[el][1][80 + b] = rh0*d1 + rh1*d4 + rh2*d7;
            s_p.f.FVT[el][2][80 + b] = rh0*d2 + rh1*d5 + rh2*d8;
            s_p.f.FS[el][96 + b] = rh0*uv0 + rh1*uv1 + rh2*uv2;   // sd
        }
    }
    __syncthreads();

    // ---- GEMM phase: feats preloaded to registers, fully unrolled loops ----
    f32x8 radv;
    #pragma unroll
    for (int l = 0; l < 8; ++l) radv[l] = s_rad[col][l];
    const int r0 = quad*4;
    f32x4 R0={0,0,0,0}, R1={0,0,0,0}, R2={0,0,0,0}, R3={0,0,0,0};
    f32x4 R4={0,0,0,0}, R5={0,0,0,0}, R6={0,0,0,0}, R7={0,0,0,0};

    if (wid == 0) {
        // z_A x {m_a tiles 0-3} -> R0-3; GEMM3 ij 0-3 -> R4-7
        const float* frow = &s_p.f.FS[col][0];
        float F[28];
        #pragma unroll
        for (int kk = 0; kk < 28; ++kk) F[kk] = frow[kk*4 + quad];
        #pragma unroll
        for (int kk = 0; kk < 28; ++kk) {
            short8 a = build2(radv, F[kk]);
            const short8* bp = B1 + (kk*7)*64 + lane;
            R0 = MFMA(a, bp[0*64], R0);
            R1 = MFMA(a, bp[1*64], R1);
            R2 = MFMA(a, bp[2*64], R2);
            R3 = MFMA(a, bp[3*64], R3);
        }
        float G[4][4];
        #pragma unroll
        for (int r = 0; r < 4; ++r)
            #pragma unroll
            for (int kk = 0; kk < 4; ++kk) G[r][kk] = s_FDT[col][r][kk*4 + quad];
        #pragma unroll
        for (int kk = 0; kk < 4; ++kk) {
            const short8 b3 = B3[kk*64 + lane];
            R4 = MFMA(build2(radv, G[0][kk]), b3, R4);
            R5 = MFMA(build2(radv, G[1][kk]), b3, R5);
            R6 = MFMA(build2(radv, G[2][kk]), b3, R6);
            R7 = MFMA(build2(radv, G[3][kk]), b3, R7);
        }
    } else if (wid == 1) {
        // z_A x {as0 t4,t5; a00 t6} -> R0-2; GEMM3 ij 4-8 -> R3-7
        const float* frow = &s_p.f.FS[col][0];
        float F[28];
        #pragma unroll
        for (int kk = 0; kk < 28; ++kk) F[kk] = frow[kk*4 + quad];
        #pragma unroll
        for (int kk = 0; kk < 28; ++kk) {
            short8 a = build2(radv, F[kk]);
            const short8* bp = B1 + (kk*7)*64 + lane;
            R0 = MFMA(a, bp[4*64], R0);
            R1 = MFMA(a, bp[5*64], R1);
            R2 = MFMA(a, bp[6*64], R2);
        }
        float G[5][4];
        #pragma unroll
        for (int r = 0; r < 5; ++r)
            #pragma unroll
            for (int kk = 0; kk < 4; ++kk) G[r][kk] = s_FDT[col][4 + r][kk*4 + quad];
        #pragma unroll
        for (int kk = 0; kk < 4; ++kk) {
            const short8 b3 = B3[kk*64 + lane];
            R3 = MFMA(build2(radv, G[0][kk]), b3, R3);
            R4 = MFMA(build2(radv, G[1][kk]), b3, R4);
            R5 = MFMA(build2(radv, G[2][kk]), b3, R5);
            R6 = MFMA(build2(radv, G[3][kk]), b3, R6);
            R7 = MFMA(build2(radv, G[4][kk]), b3, R7);
        }
    } else if (wid == 2) {
        // z_V^0 x {av0 t0,t1; aj0 t2} -> R0,R1,R2; z_V^1 x {av1 t0,t1} -> R3,R4
        const float* f0 = &s_p.f.FVT[col][0][0];
        const float* f1 = &s_p.f.FVT[col][1][0];
        float F0[24], F1[24];
        #pragma unroll
        for (int kk = 0; kk < 24; ++kk) { F0[kk] = f0[kk*4 + quad]; F1[kk] = f1[kk*4 + quad]; }
        #pragma unroll
        for (int kk = 0; kk < 24; ++kk) {
            short8 a0 = build2(radv, F0[kk]);
            short8 a1 = build2(radv, F1[kk]);
            const short8* bp = B2 + (kk*3)*64 + lane;
            short8 b0 = bp[0*64], b1 = bp[1*64], b2 = bp[2*64];
            R0 = MFMA(a0, b0, R0);
            R1 = MFMA(a0, b1, R1);
            R2 = MFMA(a0, b2, R2);
            R3 = MFMA(a1, b0, R3);
            R4 = MFMA(a1, b1, R4);
        }
    } else {
        // z_V^1 x {aj1 t2} -> R0; z_V^2 x {av2 t0,t1; aj2 t2} -> R1,R2,R3
        const float* f1 = &s_p.f.FVT[col][1][0];
        const float* f2 = &s_p.f.FVT[col][2][0];
        float F1[24], F2[24];
        #pragma unroll
        for (int kk = 0; kk < 24; ++kk) { F1[kk] = f1[kk*4 + quad]; F2[kk] = f2[kk*4 + quad]; }
        #pragma unroll
        for (int kk = 0; kk < 24; ++kk) {
            short8 a1 = build2(radv, F1[kk]);
            short8 a2 = build2(radv, F2[kk]);
            const short8* bp = B2 + (kk*3)*64 + lane;
            short8 b0 = bp[0*64], b1 = bp[1*64], b2 = bp[2*64];
            R0 = MFMA(a1, b2, R0);
            R1 = MFMA(a2, b0, R1);
            R2 = MFMA(a2, b1, R2);
            R3 = MFMA(a2, b2, R3);
        }
    }
    __syncthreads();   // feature pool retires; g (aliased) becomes writable

    // ---- spill results to (unioned) staging ----
    if (wid == 0) {
        #pragma unroll
        for (int r = 0; r < 4; ++r) {
            s_p.g.m[r0+r][ 0+col] = R0[r];
            s_p.g.m[r0+r][16+col] = R1[r];
            s_p.g.m[r0+r][32+col] = R2[r];
            s_p.g.m[r0+r][48+col] = R3[r];
            s_p.g.m[r0+r][160 + col*9 + 0] = R4[r];
            s_p.g.m[r0+r][160 + col*9 + 1] = R5[r];
            s_p.g.m[r0+r][160 + col*9 + 2] = R6[r];
            s_p.g.m[r0+r][160 + col*9 + 3] = R7[r];
        }
    } else if (wid == 1) {
        #pragma unroll
        for (int r = 0; r < 4; ++r) {
            s_p.g.as0[r0+r][ 0+col] = R0[r];
            s_p.g.as0[r0+r][16+col] = R1[r];
            s_p.g.a00[r0+r][col]    = R2[r];
            s_p.g.m[r0+r][160 + col*9 + 4] = R3[r];
            s_p.g.m[r0+r][160 + col*9 + 5] = R4[r];
            s_p.g.m[r0+r][160 + col*9 + 6] = R5[r];
            s_p.g.m[r0+r][160 + col*9 + 7] = R6[r];
            s_p.g.m[r0+r][160 + col*9 + 8] = R7[r];
        }
    } else if (wid == 2) {
        #pragma unroll
        for (int r = 0; r < 4; ++r) {
            s_p.g.m[r0+r][64 + ( 0+col)*3 + 0] = R0[r];
            s_p.g.m[r0+r][64 + (16+col)*3 + 0] = R1[r];
            s_p.g.aj[r0+r][0][col]             = R2[r];
            s_p.g.m[r0+r][64 + ( 0+col)*3 + 1] = R3[r];
            s_p.g.m[r0+r][64 + (16+col)*3 + 1] = R4[r];
        }
    } else {
        #pragma unroll
        for (int r = 0; r < 4; ++r) {
            s_p.g.aj[r0+r][1][col]             = R0[r];
            s_p.g.m[r0+r][64 + ( 0+col)*3 + 2] = R1[r];
            s_p.g.m[r0+r][64 + (16+col)*3 + 2] = R2[r];
            s_p.g.aj[r0+r][2][col]             = R3[r];
        }
    }
    __syncthreads();

    // ---- combine: recouple rh factors ----
    #pragma unroll
    for (int it = t; it < EB*32; it += NTHREADS) {
        const int el = it >> 5, c = it & 31;
        const float as0 = s_p.g.as0[el][c];
        s_p.g.m[el][64 + c*3 + 0] += s_rh[el][0]*as0;
        s_p.g.m[el][64 + c*3 + 1] += s_rh[el][1]*as0;
        s_p.g.m[el][64 + c*3 + 2] += s_rh[el][2]*as0;
    }
    {
        const int el = t >> 4, c = t & 15;
        const float a00 = s_p.g.a00[el][c];
        const float aj0 = s_p.g.aj[el][0][c], aj1 = s_p.g.aj[el][1][c], aj2 = s_p.g.aj[el][2][c];
        const float rr0 = s_rh[el][0], rr1 = s_rh[el][1], rr2 = s_rh[el][2];
        const float g0 = aj0 + rr0*a00, g1 = aj1 + rr1*a00, g2 = aj2 + rr2*a00;
        float* md = &s_p.g.m[el][160 + c*9];
        md[0] += rr0*g0; md[1] += rr0*g1; md[2] += rr0*g2;
        md[3] += rr1*g0; md[4] += rr1*g1; md[5] += rr1*g2;
        md[6] += rr2*g0; md[7] += rr2*g1; md[8] += rr2*g2;
    }
    __syncthreads();

    // ---- segmented emit: s_dst non-decreasing -> one atomic per (segment, channel) ----
    for (int ch = t; ch < OUT_CH; ch += NTHREADS) {
        float run = 0.0f;
        #pragma unroll
        for (int el = 0; el < EB; ++el) {
            run += s_p.g.m[el][ch];
            if (el == EB-1 || s_dst[el+1] != s_dst[el]) {
                atomicAdd(&out[(size_t)s_dst[el]*OUT_CH + ch], run);
                run = 0.0f;
            }
        }
    }
}

extern "C" void kernel_launch(void* const* d_in, const int* in_sizes, int n_in,
                              void* d_out, int out_size, void* d_ws, size_t ws_size,
                              hipStream_t stream)
{
    const float* xa  = (const float*)d_in[0];
    const float* xv  = (const float*)d_in[1];
    const float* xd  = (const float*)d_in[2];
    const float* rij = (const float*)d_in[3];
    const float* P000 = (const float*)d_in[4];
    const float* P110 = (const float*)d_in[5];
    const float* P220 = (const float*)d_in[6];
    const float* P011 = (const float*)d_in[7];
    const float* P101 = (const float*)d_in[8];
    const float* P121 = (const float*)d_in[9];
    const float* P211 = (const float*)d_in[10];
    const float* P111 = (const float*)d_in[11];
    const float* P022 = (const float*)d_in[12];
    const float* P112 = (const float*)d_in[13];
    const float* P202 = (const float*)d_in[14];
    const float* P222 = (const float*)d_in[15];
    const float* P212 = (const float*)d_in[16];
    const int* src = (const int*)d_in[17];
    const int* dst = (const int*)d_in[18];

    unsigned short* BP = (unsigned short*)d_ws;
    int* ip     = (int*)d_ws + (NPACK/2);
    int* cnt    = ip;
    int* off    = ip + NODES;
    int* cursor = off + NODES + 1;
    int* eidx   = cursor + NODES;

    hipMemsetAsync(cnt, 0, NODES * sizeof(int), stream);
    hipMemsetAsync(d_out, 0, (size_t)out_size * sizeof(float), stream);

    prep_kernel<<<EDGES/256, 256, 0, stream>>>(
        P000, P110, P220, P011, P101, P121, P211, P111,
        P022, P112, P202, P222, P212, BP, dst, cnt);
    scan_kernel   <<<1,         256, 0, stream>>>(cnt, off, cursor);
    scatter_kernel<<<EDGES/256, 256, 0, stream>>>(dst, cursor, eidx);

    edge_kernel<<<EDGES/EB, NTHREADS, 0, stream>>>(
        xa, xv, xd, rij, BP, src, dst, eidx, (float*)d_out);
}

// Round 12
// 374.480 us; speedup vs baseline: 1.1155x; 1.1155x over previous
//
#include <hip/hip_runtime.h>

#define NODES    16384
#define EDGES    262144
#define OUT_CH   304      // 64 + 32*3 + 16*9
#define EB       32       // edges per block
#define NTHREADS 512

typedef __attribute__((ext_vector_type(8))) short short8;
typedef __attribute__((ext_vector_type(4))) float f32x4;
typedef __attribute__((ext_vector_type(8))) float f32x8;
typedef __attribute__((ext_vector_type(8))) __bf16 bf16x8;
#define MFMA(a,b,c) __builtin_amdgcn_mfma_f32_16x16x32_bf16((a),(b),(c),0,0,0)

// ---------- packed-B (bf16) sizes ----------
#define NB1 100352
#define NB2 36864
#define NB3 2048
#define NPACK (NB1 + NB2 + NB3)     // 139264 ushort = 278528 B

// ---------------- fused prepack(B) + count kernel ----------------
// K-order: k = b*8 + l  (fragment of 8 consecutive k = one b, all 8 l)
__global__ __launch_bounds__(256) void prep_kernel(
    const float* __restrict__ P000, const float* __restrict__ P110, const float* __restrict__ P220,
    const float* __restrict__ P011, const float* __restrict__ P101, const float* __restrict__ P121,
    const float* __restrict__ P211, const float* __restrict__ P111,
    const float* __restrict__ P022, const float* __restrict__ P112, const float* __restrict__ P202,
    const float* __restrict__ P222, const float* __restrict__ P212,
    unsigned short* __restrict__ BP,
    const int* __restrict__ dst, int* __restrict__ cnt)
{
    int idx = blockIdx.x*256 + threadIdx.x;
    if (idx < NPACK) {
        float v = 0.0f;
        if (idx < NB1) {                       // GEMM1: BW=112
            int j = idx & 7, lane = (idx >> 3) & 63, q = idx >> 9;
            int tile = q % 7, kk = q / 7;
            int n = tile*16 + (lane & 15);
            int k = kk*32 + (lane >> 4)*8 + j;
            int l = k & 7, b = k >> 3;
            if (n < 64) {           int c = n;
                if      (b <  64) v = P000[(c*8+l)*64 + b];
                else if (b <  96) v = P110[(c*8+l)*32 + (b-64)];
                else              v = P220[(c*8+l)*16 + (b-96)];
            } else if (n < 96) {    int c = n - 64;      // as0
                if      (b <  64) v = P101[(c*8+l)*64 + b];
                else if (b <  96) v = P211[(c*8+l)*32 + (b-64)];
            } else {                int c = n - 96;      // a00
                if      (b <  64) v = P202[(c*8+l)*64 + b];
            }
        } else if (idx < NB1 + NB2) {          // GEMM2: BW=96
            int o = idx - NB1;
            int j = o & 7, lane = (o >> 3) & 63, q = o >> 9;
            int tile = q % 3, kk = q / 3;
            int n = tile*16 + (lane & 15);
            int k = kk*32 + (lane >> 4)*8 + j;
            int l = k & 7, b = k >> 3;
            if (n < 32) {           int c = n;           // av
                if      (b <  32) v = P011[(c*8+l)*32 + b];
                else if (b <  48) v = P121[(c*8+l)*16 + (b-32)];
                else if (b <  80) v = P111[(c*8+l)*32 + (b-48)];
            } else {                int c = n - 32;      // aj
                if      (b <  32) v = P112[(c*8+l)*32 + b];
                else if (b <  48) v = 0.0f;
                else if (b <  80) v = P212[(c*8+l)*32 + (b-48)];
                else              v = P222[(c*8+l)*16 + (b-80)];
            }
        } else {                               // GEMM3: BW=16
            int o = idx - NB1 - NB2;
            int j = o & 7, lane = (o >> 3) & 63, kk = o >> 9;
            int n = lane & 15;
            int k = kk*32 + (lane >> 4)*8 + j;
            int l = k & 7, b = k >> 3;
            v = P022[(n*8+l)*16 + b];
        }
        union { float f; unsigned int i; } x; x.f = v;
        unsigned int i = x.i;
        i += 0x7fffu + ((i >> 16) & 1u);
        BP[idx] = (unsigned short)(i >> 16);
    }
    if (idx < EDGES) atomicAdd(&cnt[dst[idx]], 1);
}

// ---------------- CSR scan + scatter ----------------
__global__ __launch_bounds__(1024) void scan_kernel(const int* __restrict__ cnt,
                                                    int* __restrict__ off,
                                                    int* __restrict__ cursor)
{
    __shared__ int s_part[1024];
    const int t = threadIdx.x;
    const int base = t * 16;           // 1024 x 16 = 16384
    int sum = 0;
    for (int i = 0; i < 16; ++i) sum += cnt[base + i];
    s_part[t] = sum;
    __syncthreads();
    for (int d = 1; d < 1024; d <<= 1) {
        int add = (t >= d) ? s_part[t - d] : 0;
        __syncthreads();
        s_part[t] += add;
        __syncthreads();
    }
    int run = s_part[t] - sum;
    for (int i = 0; i < 16; ++i) {
        int c = cnt[base + i];
        off[base + i]    = run;
        cursor[base + i] = run;
        run += c;
    }
    if (t == 1023) off[NODES] = run;
}

__global__ __launch_bounds__(256) void scatter_kernel(const int* __restrict__ dst,
                                                      int* __restrict__ cursor,
                                                      int* __restrict__ eidx)
{
    int e = blockIdx.x*256 + threadIdx.x;
    if (e < EDGES) {
        int pos = atomicAdd(&cursor[dst[e]], 1);
        eidx[pos] = e;
    }
}

// A-fragment: one feature element x the full (in-register) rad vector
__device__ __forceinline__ short8 build2(const f32x8 radv, float f)
{
    f32x8 z = radv * f;
    bf16x8 zb = __builtin_convertvector(z, bf16x8);
    union { bf16x8 b; short8 s; } w; w.b = zb;
    return w.s;
}

// feature pool (dead after GEMM loops) unioned with result staging
struct FeatPool {
    float FS[EB][116];       // xa[0,64) sv[64,96) sd[96,112)
    float FVT[EB][3][100];   // [i][b]: xv[0,32) uv[32,48) cr[48,80) wd[80,96)
};                           // 53248 B
struct MsgPool {
    float m[EB][308];        // 39424 B
    float as0[EB][32];       //  4096 B
    float a00[EB][16];       //  2048 B
    float aj[EB][3][16];     //  6144 B
};                           // 51712 B
union Pool {
    FeatPool f;
    MsgPool  g;
};

// ---------------- main edge kernel: M=32 per block, B-tile reuse x2 ----------------
__global__ __launch_bounds__(NTHREADS, 4) void edge_kernel(
    const float* __restrict__ xa_g, const float* __restrict__ xv_g, const float* __restrict__ xd_g,
    const float* __restrict__ rij_g,
    const unsigned short* __restrict__ BP,
    const int* __restrict__ src, const int* __restrict__ dst, const int* __restrict__ eidx,
    float* __restrict__ out)
{
    __shared__ __align__(16) Pool s_p;
    __shared__ __align__(16) float s_FDT[EB][9][20];   // [ij][b<16]
    __shared__ float s_rad[EB][9];
    __shared__ float s_rh[EB][4];
    __shared__ int   s_dst[EB];
    __shared__ int   s_srcn[EB];

    const int t  = threadIdx.x;
    const int e0 = blockIdx.x * EB;
    const int lane = t & 63, wid = t >> 6;
    const int col = lane & 15, quad = lane >> 4;

    const short8* __restrict__ B1 = (const short8*)BP;
    const short8* __restrict__ B2 = (const short8*)(BP + NB1);
    const short8* __restrict__ B3 = (const short8*)(BP + NB1 + NB2);

    // ---- phase 1a: per-edge radial basis + rh ----
    if (t < EB) {
        const int e = eidx[e0 + t];            // CSR order: s_dst non-decreasing
        float r0 = rij_g[e*3+0];
        float r1 = rij_g[e*3+1];
        float r2 = rij_g[e*3+2];
        float x_sq = (r0*r0 + r1*r1 + r2*r2) * 0.125f;
        float q  = sqrtf(x_sq);
        float w  = fmaxf(1.0f - x_sq, 0.0f);
        const float PI = 3.14159265358979323846f;
        for (int n = 0; n < 8; ++n)
            s_rad[t][n] = cosf(PI * (float)n * q) * w;
        float y0 = r0*0.875f, y1 = r1*0.875f, y2 = r2*0.875f;
        float nn = sqrtf(y0*y0 + y1*y1 + y2*y2);
        float sc = tanhf(nn) / fmaxf(nn, 1e-6f);
        s_rh[t][0] = y0*sc; s_rh[t][1] = y1*sc; s_rh[t][2] = y2*sc; s_rh[t][3] = 0.f;
        s_dst[t]  = dst[e];
        s_srcn[t] = src[e];
    }
    __syncthreads();

    // ---- phase 1b: gather node features into LDS (verified math/layout) ----
    {
        const int el  = t >> 4;                // 0..31
        const int sub = t & 15;
        const int n   = s_srcn[el];
        const float rh0 = s_rh[el][0], rh1 = s_rh[el][1], rh2 = s_rh[el][2];
        #pragma unroll
        for (int k = 0; k < 4; ++k) {
            int b = sub + 16*k;
            s_p.f.FS[el][b] = xa_g[n*64 + b];
        }
        #pragma unroll
        for (int k = 0; k < 2; ++k) {
            int b = sub + 16*k;
            float v0 = xv_g[(n*32 + b)*3 + 0];
            float v1 = xv_g[(n*32 + b)*3 + 1];
            float v2 = xv_g[(n*32 + b)*3 + 2];
            s_p.f.FVT[el][0][b] = v0;
            s_p.f.FVT[el][1][b] = v1;
            s_p.f.FVT[el][2][b] = v2;
            s_p.f.FS[el][64 + b] = rh0*v0 + rh1*v1 + rh2*v2;      // sv
            s_p.f.FVT[el][0][48 + b] = rh1*v2 - rh2*v1;           // cr
            s_p.f.FVT[el][1][48 + b] = rh2*v0 - rh0*v2;
            s_p.f.FVT[el][2][48 + b] = rh0*v1 - rh1*v0;
        }
        {
            const int b = sub;
            const float d0 = xd_g[(n*16+b)*9+0], d1 = xd_g[(n*16+b)*9+1], d2 = xd_g[(n*16+b)*9+2];
            const float d3 = xd_g[(n*16+b)*9+3], d4 = xd_g[(n*16+b)*9+4], d5 = xd_g[(n*16+b)*9+5];
            const float d6 = xd_g[(n*16+b)*9+6], d7 = xd_g[(n*16+b)*9+7], d8 = xd_g[(n*16+b)*9+8];
            s_FDT[el][0][b]=d0; s_FDT[el][1][b]=d1; s_FDT[el][2][b]=d2;
            s_FDT[el][3][b]=d3; s_FDT[el][4][b]=d4; s_FDT[el][5][b]=d5;
            s_FDT[el][6][b]=d6; s_FDT[el][7][b]=d7; s_FDT[el][8][b]=d8;
            const float uv0 = d0*rh0 + d1*rh1 + d2*rh2;
            const float uv1 = d3*rh0 + d4*rh1 + d5*rh2;
            const float uv2 = d6*rh0 + d7*rh1 + d8*rh2;
            s_p.f.FVT[el][0][32 + b] = uv0;
            s_p.f.FVT[el][1][32 + b] = uv1;
            s_p.f.FVT[el][2][32 + b] = uv2;
            s_p.f.FVT[el][0][80 + b] = rh0*d0 + rh1*d3 + rh2*d6;  // wd
            s_p.f.FVT[el][1][80 + b] = rh0*d1 + rh1*d4 + rh2*d7;
            s_p.f.FVT[el][2][80 + b] = rh0*d2 + rh1*d5 + rh2*d8;
            s_p.f.FS[el][96 + b] = rh0*uv0 + rh1*uv1 + rh2*uv2;   // sd
        }
    }
    __syncthreads();

    // ---- GEMM phase: each wave applies each B-tile to TWO A-fragments ----
    f32x8 radv_lo, radv_hi;
    #pragma unroll
    for (int l = 0; l < 8; ++l) { radv_lo[l] = s_rad[col][l]; radv_hi[l] = s_rad[16+col][l]; }
    const int r0 = quad*4;
    // accumulators (max 10 used)
    f32x4 A0={0,0,0,0}, A1={0,0,0,0}, A2={0,0,0,0}, A3={0,0,0,0}, A4={0,0,0,0};
    f32x4 A5={0,0,0,0}, A6={0,0,0,0}, A7={0,0,0,0}, A8={0,0,0,0}, A9={0,0,0,0};

    if (wid < 3) {
        // G1 tile-pairs: w0 {0,1}, w1 {2,3}, w2 {4,5}
        const int Ta = wid*2, Tb = wid*2 + 1;
        for (int kk = 0; kk < 28; ++kk) {
            short8 al = build2(radv_lo, s_p.f.FS[col][kk*4 + quad]);
            short8 ah = build2(radv_hi, s_p.f.FS[16+col][kk*4 + quad]);
            const short8* bp = B1 + (kk*7)*64 + lane;
            short8 bA = bp[Ta*64], bB = bp[Tb*64];
            A0 = MFMA(al, bA, A0);  A1 = MFMA(ah, bA, A1);
            A2 = MFMA(al, bB, A2);  A3 = MFMA(ah, bB, A3);
        }
    } else if (wid == 3) {
        // G1 t6 (a00) + G2 comp2 tile0 (av2 cols 0-15)
        for (int kk = 0; kk < 28; ++kk) {
            short8 al = build2(radv_lo, s_p.f.FS[col][kk*4 + quad]);
            short8 ah = build2(radv_hi, s_p.f.FS[16+col][kk*4 + quad]);
            short8 b = B1[(kk*7 + 6)*64 + lane];
            A0 = MFMA(al, b, A0);  A1 = MFMA(ah, b, A1);
        }
        for (int kk = 0; kk < 24; ++kk) {
            short8 al = build2(radv_lo, s_p.f.FVT[col][2][kk*4 + quad]);
            short8 ah = build2(radv_hi, s_p.f.FVT[16+col][2][kk*4 + quad]);
            short8 b = B2[(kk*3 + 0)*64 + lane];
            A2 = MFMA(al, b, A2);  A3 = MFMA(ah, b, A3);
        }
    } else if (wid == 4) {
        // G2 comp0 tiles {0,1} + G3 ij0,1,2
        for (int kk = 0; kk < 24; ++kk) {
            short8 al = build2(radv_lo, s_p.f.FVT[col][0][kk*4 + quad]);
            short8 ah = build2(radv_hi, s_p.f.FVT[16+col][0][kk*4 + quad]);
            const short8* bp = B2 + (kk*3)*64 + lane;
            short8 b0 = bp[0*64], b1 = bp[1*64];
            A0 = MFMA(al, b0, A0);  A1 = MFMA(ah, b0, A1);
            A2 = MFMA(al, b1, A2);  A3 = MFMA(ah, b1, A3);
        }
        #pragma unroll
        for (int kk = 0; kk < 4; ++kk) {
            short8 b = B3[kk*64 + lane];
            A4 = MFMA(build2(radv_lo, s_FDT[col][0][kk*4+quad]), b, A4);
            A5 = MFMA(build2(radv_hi, s_FDT[16+col][0][kk*4+quad]), b, A5);
            A6 = MFMA(build2(radv_lo, s_FDT[col][1][kk*4+quad]), b, A6);
            A7 = MFMA(build2(radv_hi, s_FDT[16+col][1][kk*4+quad]), b, A7);
            A8 = MFMA(build2(radv_lo, s_FDT[col][2][kk*4+quad]), b, A8);
            A9 = MFMA(build2(radv_hi, s_FDT[16+col][2][kk*4+quad]), b, A9);
        }
    } else if (wid == 5) {
        // G2 aj0 (comp0 t2) + comp1 tile0 + G3 ij3,4
        for (int kk = 0; kk < 24; ++kk) {
            short8 a0l = build2(radv_lo, s_p.f.FVT[col][0][kk*4 + quad]);
            short8 a0h = build2(radv_hi, s_p.f.FVT[16+col][0][kk*4 + quad]);
            short8 a1l = build2(radv_lo, s_p.f.FVT[col][1][kk*4 + quad]);
            short8 a1h = build2(radv_hi, s_p.f.FVT[16+col][1][kk*4 + quad]);
            const short8* bp = B2 + (kk*3)*64 + lane;
            short8 b2 = bp[2*64], b0 = bp[0*64];
            A0 = MFMA(a0l, b2, A0);  A1 = MFMA(a0h, b2, A1);
            A2 = MFMA(a1l, b0, A2);  A3 = MFMA(a1h, b0, A3);
        }
        #pragma unroll
        for (int kk = 0; kk < 4; ++kk) {
            short8 b = B3[kk*64 + lane];
            A4 = MFMA(build2(radv_lo, s_FDT[col][3][kk*4+quad]), b, A4);
            A5 = MFMA(build2(radv_hi, s_FDT[16+col][3][kk*4+quad]), b, A5);
            A6 = MFMA(build2(radv_lo, s_FDT[col][4][kk*4+quad]), b, A6);
            A7 = MFMA(build2(radv_hi, s_FDT[16+col][4][kk*4+quad]), b, A7);
        }
    } else if (wid == 6) {
        // G2 comp1 tiles {1,2} + G3 ij5,6
        for (int kk = 0; kk < 24; ++kk) {
            short8 al = build2(radv_lo, s_p.f.FVT[col][1][kk*4 + quad]);
            short8 ah = build2(radv_hi, s_p.f.FVT[16+col][1][kk*4 + quad]);
            const short8* bp = B2 + (kk*3)*64 + lane;
            short8 b1 = bp[1*64], b2 = bp[2*64];
            A0 = MFMA(al, b1, A0);  A1 = MFMA(ah, b1, A1);
            A2 = MFMA(al, b2, A2);  A3 = MFMA(ah, b2, A3);
        }
        #pragma unroll
        for (int kk = 0; kk < 4; ++kk) {
            short8 b = B3[kk*64 + lane];
            A4 = MFMA(build2(radv_lo, s_FDT[col][5][kk*4+quad]), b, A4);
            A5 = MFMA(build2(radv_hi, s_FDT[16+col][5][kk*4+quad]), b, A5);
            A6 = MFMA(build2(radv_lo, s_FDT[col][6][kk*4+quad]), b, A6);
            A7 = MFMA(build2(radv_hi, s_FDT[16+col][6][kk*4+quad]), b, A7);
        }
    } else {
        // G2 comp2 tiles {1,2} + G3 ij7,8
        for (int kk = 0; kk < 24; ++kk) {
            short8 al = build2(radv_lo, s_p.f.FVT[col][2][kk*4 + quad]);
            short8 ah = build2(radv_hi, s_p.f.FVT[16+col][2][kk*4 + quad]);
            const short8* bp = B2 + (kk*3)*64 + lane;
            short8 b1 = bp[1*64], b2 = bp[2*64];
            A0 = MFMA(al, b1, A0);  A1 = MFMA(ah, b1, A1);
            A2 = MFMA(al, b2, A2);  A3 = MFMA(ah, b2, A3);
        }
        #pragma unroll
        for (int kk = 0; kk < 4; ++kk) {
            short8 b = B3[kk*64 + lane];
            A4 = MFMA(build2(radv_lo, s_FDT[col][7][kk*4+quad]), b, A4);
            A5 = MFMA(build2(radv_hi, s_FDT[16+col][7][kk*4+quad]), b, A5);
            A6 = MFMA(build2(radv_lo, s_FDT[col][8][kk*4+quad]), b, A6);
            A7 = MFMA(build2(radv_hi, s_FDT[16+col][8][kk*4+quad]), b, A7);
        }
    }
    __syncthreads();   // feature pool retires; g (aliased) becomes writable

    // ---- spill results to (unioned) staging ----
    // D row = quad*4+r: lo edge = r0+r, hi edge = 16+r0+r; col = channel sub-index
    if (wid < 3) {
        const int Ta = wid*2, Tb = wid*2 + 1;   // G1 tiles -> n-cols Ta*16+col, Tb*16+col
        #pragma unroll
        for (int r = 0; r < 4; ++r) {
            const int elo = r0+r, ehi = 16+r0+r;
            if (wid < 2) {          // m_a channels
                s_p.g.m[elo][Ta*16+col] = A0[r];
                s_p.g.m[ehi][Ta*16+col] = A1[r];
                s_p.g.m[elo][Tb*16+col] = A2[r];
                s_p.g.m[ehi][Tb*16+col] = A3[r];
            } else {                // as0 (tiles 4,5 -> c = col, 16+col)
                s_p.g.as0[elo][col]    = A0[r];
                s_p.g.as0[ehi][col]    = A1[r];
                s_p.g.as0[elo][16+col] = A2[r];
                s_p.g.as0[ehi][16+col] = A3[r];
            }
        }
    } else if (wid == 3) {
        #pragma unroll
        for (int r = 0; r < 4; ++r) {
            const int elo = r0+r, ehi = 16+r0+r;
            s_p.g.a00[elo][col] = A0[r];
            s_p.g.a00[ehi][col] = A1[r];
            s_p.g.m[elo][64 + col*3 + 2] = A2[r];      // av2 cols 0-15
            s_p.g.m[ehi][64 + col*3 + 2] = A3[r];
        }
    } else if (wid == 4) {
        #pragma unroll
        for (int r = 0; r < 4; ++r) {
            const int elo = r0+r, ehi = 16+r0+r;
            s_p.g.m[elo][64 + col*3 + 0]      = A0[r];
            s_p.g.m[ehi][64 + col*3 + 0]      = A1[r];
            s_p.g.m[elo][64 + (16+col)*3 + 0] = A2[r];
            s_p.g.m[ehi][64 + (16+col)*3 + 0] = A3[r];
            s_p.g.m[elo][160 + col*9 + 0] = A4[r];
            s_p.g.m[ehi][160 + col*9 + 0] = A5[r];
            s_p.g.m[elo][160 + col*9 + 1] = A6[r];
            s_p.g.m[ehi][160 + col*9 + 1] = A7[r];
            s_p.g.m[elo][160 + col*9 + 2] = A8[r];
            s_p.g.m[ehi][160 + col*9 + 2] = A9[r];
        }
    } else if (wid == 5) {
        #pragma unroll
        for (int r = 0; r < 4; ++r) {
            const int elo = r0+r, ehi = 16+r0+r;
            s_p.g.aj[elo][0][col] = A0[r];
            s_p.g.aj[ehi][0][col] = A1[r];
            s_p.g.m[elo][64 + col*3 + 1] = A2[r];
            s_p.g.m[ehi][64 + col*3 + 1] = A3[r];
            s_p.g.m[elo][160 + col*9 + 3] = A4[r];
            s_p.g.m[ehi][160 + col*9 + 3] = A5[r];
            s_p.g.m[elo][160 + col*9 + 4] = A6[r];
            s_p.g.m[ehi][160 + col*9 + 4] = A7[r];
        }
    } else if (wid == 6) {
        #pragma unroll
        for (int r = 0; r < 4; ++r) {
            const int elo = r0+r, ehi = 16+r0+r;
            s_p.g.m[elo][64 + (16+col)*3 + 1] = A0[r];
            s_p.g.m[ehi][64 + (16+col)*3 + 1] = A1[r];
            s_p.g.aj[elo][1][col] = A2[r];
            s_p.g.aj[ehi][1][col] = A3[r];
            s_p.g.m[elo][160 + col*9 + 5] = A4[r];
            s_p.g.m[ehi][160 + col*9 + 5] = A5[r];
            s_p.g.m[elo][160 + col*9 + 6] = A6[r];
            s_p.g.m[ehi][160 + col*9 + 6] = A7[r];
        }
    } else {
        #pragma unroll
        for (int r = 0; r < 4; ++r) {
            const int elo = r0+r, ehi = 16+r0+r;
            s_p.g.m[elo][64 + (16+col)*3 + 2] = A0[r];
            s_p.g.m[ehi][64 + (16+col)*3 + 2] = A1[r];
            s_p.g.aj[elo][2][col] = A2[r];
            s_p.g.aj[ehi][2][col] = A3[r];
            s_p.g.m[elo][160 + col*9 + 7] = A4[r];
            s_p.g.m[ehi][160 + col*9 + 7] = A5[r];
            s_p.g.m[elo][160 + col*9 + 8] = A6[r];
            s_p.g.m[ehi][160 + col*9 + 8] = A7[r];
        }
    }
    __syncthreads();

    // ---- combine: recouple rh factors ----
    #pragma unroll
    for (int it = t; it < EB*32; it += NTHREADS) {
        const int el = it >> 5, c = it & 31;
        const float as0 = s_p.g.as0[el][c];
        s_p.g.m[el][64 + c*3 + 0] += s_rh[el][0]*as0;
        s_p.g.m[el][64 + c*3 + 1] += s_rh[el][1]*as0;
        s_p.g.m[el][64 + c*3 + 2] += s_rh[el][2]*as0;
    }
    {
        const int el = t >> 4, c = t & 15;     // 512 threads = 32 el x 16 c exactly
        const float a00 = s_p.g.a00[el][c];
        const float aj0 = s_p.g.aj[el][0][c], aj1 = s_p.g.aj[el][1][c], aj2 = s_p.g.aj[el][2][c];
        const float rr0 = s_rh[el][0], rr1 = s_rh[el][1], rr2 = s_rh[el][2];
        const float g0 = aj0 + rr0*a00, g1 = aj1 + rr1*a00, g2 = aj2 + rr2*a00;
        float* md = &s_p.g.m[el][160 + c*9];
        md[0] += rr0*g0; md[1] += rr0*g1; md[2] += rr0*g2;
        md[3] += rr1*g0; md[4] += rr1*g1; md[5] += rr1*g2;
        md[6] += rr2*g0; md[7] += rr2*g1; md[8] += rr2*g2;
    }
    __syncthreads();

    // ---- segmented emit: s_dst non-decreasing -> one atomic per (segment, channel) ----
    for (int ch = t; ch < OUT_CH; ch += NTHREADS) {
        float run = 0.0f;
        #pragma unroll
        for (int el = 0; el < EB; ++el) {
            run += s_p.g.m[el][ch];
            if (el == EB-1 || s_dst[el+1] != s_dst[el]) {
                atomicAdd(&out[(size_t)s_dst[el]*OUT_CH + ch], run);
                run = 0.0f;
            }
        }
    }
}

extern "C" void kernel_launch(void* const* d_in, const int* in_sizes, int n_in,
                              void* d_out, int out_size, void* d_ws, size_t ws_size,
                              hipStream_t stream)
{
    const float* xa  = (const float*)d_in[0];
    const float* xv  = (const float*)d_in[1];
    const float* xd  = (const float*)d_in[2];
    const float* rij = (const float*)d_in[3];
    const float* P000 = (const float*)d_in[4];
    const float* P110 = (const float*)d_in[5];
    const float* P220 = (const float*)d_in[6];
    const float* P011 = (const float*)d_in[7];
    const float* P101 = (const float*)d_in[8];
    const float* P121 = (const float*)d_in[9];
    const float* P211 = (const float*)d_in[10];
    const float* P111 = (const float*)d_in[11];
    const float* P022 = (const float*)d_in[12];
    const float* P112 = (const float*)d_in[13];
    const float* P202 = (const float*)d_in[14];
    const float* P222 = (const float*)d_in[15];
    const float* P212 = (const float*)d_in[16];
    const int* src = (const int*)d_in[17];
    const int* dst = (const int*)d_in[18];

    unsigned short* BP = (unsigned short*)d_ws;
    int* ip     = (int*)d_ws + (NPACK/2);
    int* cnt    = ip;
    int* off    = ip + NODES;
    int* cursor = off + NODES + 1;
    int* eidx   = cursor + NODES;

    hipMemsetAsync(cnt, 0, NODES * sizeof(int), stream);
    hipMemsetAsync(d_out, 0, (size_t)out_size * sizeof(float), stream);

    prep_kernel<<<EDGES/256, 256, 0, stream>>>(
        P000, P110, P220, P011, P101, P121, P211, P111,
        P022, P112, P202, P222, P212, BP, dst, cnt);
    scan_kernel   <<<1,        1024, 0, stream>>>(cnt, off, cursor);
    scatter_kernel<<<EDGES/256, 256, 0, stream>>>(dst, cursor, eidx);

    edge_kernel<<<EDGES/EB, NTHREADS, 0, stream>>>(
        xa, xv, xd, rij, BP, src, dst, eidx, (float*)d_out);
}